// Round 1
// baseline (56.764 us; speedup 1.0000x reference)
//
#include <hip/hip_runtime.h>

// QuantumAttention: out[b,s,e] = sum_q q[b,s,q] * W_dec[e,q] + x[b,s,e]
//   angles = x @ W_enc^T  ([B,S,Q]), c = cos(angles)
//   q[0] = prod(c[1..Q-1]);  q[i] = prod(c[0..i]) for i>=1
//
// B*S = 16384 tokens, E = 1024, Q = 8. Memory-bound: 64 MiB in + 64 MiB out.

#define EDIM 1024
#define QDIM 8
#define NTOK 16384
#define BLOCK 256
#define GRID 1024          // 16 tokens per block, contiguous chunk

__global__ __launch_bounds__(BLOCK, 4)
void qattn_kernel(const float* __restrict__ x,
                  const float* __restrict__ W_enc,   // [Q][E]
                  const float* __restrict__ W_dec,   // [E][Q]
                  float* __restrict__ out)
{
    __shared__ float red[2][4 * QDIM];   // [slot][wave*Q + q]

    const int t    = threadIdx.x;     // 0..255
    const int lane = t & 63;
    const int wave = t >> 6;
    const int e0   = t * 4;           // this thread's 4 embed elements

    // ---- preload weight slices into registers (once per block) ----
    float wenc[QDIM][4];
#pragma unroll
    for (int q = 0; q < QDIM; ++q) {
        float4 w = *(const float4*)(W_enc + q * EDIM + e0);
        wenc[q][0] = w.x; wenc[q][1] = w.y; wenc[q][2] = w.z; wenc[q][3] = w.w;
    }
    float wdec[4][QDIM];
#pragma unroll
    for (int j = 0; j < 4; ++j) {
        float4 a = *(const float4*)(W_dec + (e0 + j) * QDIM);
        float4 b = *(const float4*)(W_dec + (e0 + j) * QDIM + 4);
        wdec[j][0] = a.x; wdec[j][1] = a.y; wdec[j][2] = a.z; wdec[j][3] = a.w;
        wdec[j][4] = b.x; wdec[j][5] = b.y; wdec[j][6] = b.z; wdec[j][7] = b.w;
    }

    const int tok0   = blockIdx.x * (NTOK / GRID);
    const int tokEnd = tok0 + (NTOK / GRID);

    // prefetch first token's x
    float4 xv = *(const float4*)(x + (size_t)tok0 * EDIM + e0);

    int slot = 0;
    for (int i = tok0; i < tokEnd; ++i, slot ^= 1) {
        // prefetch next token's x (hides HBM latency under reduce/compute)
        float4 xn = make_float4(0.f, 0.f, 0.f, 0.f);
        if (i + 1 < tokEnd)
            xn = *(const float4*)(x + (size_t)(i + 1) * EDIM + e0);

        // ---- encode: per-thread partial dot products ----
        float partial[QDIM];
#pragma unroll
        for (int q = 0; q < QDIM; ++q)
            partial[q] = xv.x * wenc[q][0] + xv.y * wenc[q][1]
                       + xv.z * wenc[q][2] + xv.w * wenc[q][3];

        // ---- 64-lane butterfly reduce ----
#pragma unroll
        for (int off = 32; off >= 1; off >>= 1) {
#pragma unroll
            for (int q = 0; q < QDIM; ++q)
                partial[q] += __shfl_xor(partial[q], off, 64);
        }

        // ---- cross-wave combine via LDS (double-buffered, 1 barrier/token) ----
        if (lane == 0) {
#pragma unroll
            for (int q = 0; q < QDIM; ++q)
                red[slot][wave * QDIM + q] = partial[q];
        }
        __syncthreads();

        float c[QDIM];
#pragma unroll
        for (int q = 0; q < QDIM; ++q) {
            float ang = red[slot][0 * QDIM + q] + red[slot][1 * QDIM + q]
                      + red[slot][2 * QDIM + q] + red[slot][3 * QDIM + q];
            c[q] = __cosf(ang);
        }

        // ---- q-values: q[0] = c1*...*c7 ; q[i] = c0*...*ci ----
        float qv[QDIM];
        float q0 = c[1];
#pragma unroll
        for (int q = 2; q < QDIM; ++q) q0 *= c[q];
        qv[0] = q0;
        float p = c[0];
#pragma unroll
        for (int q = 1; q < QDIM; ++q) { p *= c[q]; qv[q] = p; }

        // ---- decode + residual, coalesced float4 store ----
        float4 o = xv;
#pragma unroll
        for (int q = 0; q < QDIM; ++q) {
            o.x += qv[q] * wdec[0][q];
            o.y += qv[q] * wdec[1][q];
            o.z += qv[q] * wdec[2][q];
            o.w += qv[q] * wdec[3][q];
        }
        *(float4*)(out + (size_t)i * EDIM + e0) = o;

        xv = xn;
    }
}

extern "C" void kernel_launch(void* const* d_in, const int* in_sizes, int n_in,
                              void* d_out, int out_size, void* d_ws, size_t ws_size,
                              hipStream_t stream) {
    const float* x     = (const float*)d_in[0];
    const float* W_enc = (const float*)d_in[1];
    const float* W_dec = (const float*)d_in[2];
    float* out         = (float*)d_out;

    hipLaunchKernelGGL(qattn_kernel, dim3(GRID), dim3(BLOCK), 0, stream,
                       x, W_enc, W_dec, out);
}

// Round 2
// 49.206 us; speedup vs baseline: 1.1536x; 1.1536x over previous
//
#include <hip/hip_runtime.h>

// QuantumAttention: out[b,s,e] = sum_q q[b,s,q] * W_dec[e,q] + x[b,s,e]
//   angles = x @ W_enc^T  ([B,S,Q]), c = cos(angles)
//   q[0] = prod(c[1..Q-1]);  q[i] = prod(c[0..i]) for i>=1
//
// B*S = 16384 tokens, E = 1024, Q = 8. Memory floor ~20us (x in + out out).
// R2: T=4 tokens per block, single barrier, grid 4096 -> kill the R1
// latency-bound regime (occ 30%, VALUBusy 21%).

#define EDIM 1024
#define QDIM 8
#define NTOK 16384
#define BLOCK 256
#define T 4                    // tokens per block (one shot, no loop)
#define GRID (NTOK / T)        // 4096 blocks

__global__ __launch_bounds__(BLOCK)
void qattn_kernel(const float* __restrict__ x,
                  const float* __restrict__ W_enc,   // [Q][E]
                  const float* __restrict__ W_dec,   // [E][Q]
                  float* __restrict__ out)
{
    __shared__ float red[T][4][QDIM];   // [tok][wave][q] = 128 floats

    const int t    = threadIdx.x;     // 0..255
    const int lane = t & 63;
    const int wave = t >> 6;
    const int e0   = t * 4;           // this thread's 4 embed elements

    // ---- weight slices into registers (once per block) ----
    float wenc[QDIM][4];
#pragma unroll
    for (int q = 0; q < QDIM; ++q) {
        float4 w = *(const float4*)(W_enc + q * EDIM + e0);
        wenc[q][0] = w.x; wenc[q][1] = w.y; wenc[q][2] = w.z; wenc[q][3] = w.w;
    }
    float wdec[4][QDIM];
#pragma unroll
    for (int j = 0; j < 4; ++j) {
        float4 a = *(const float4*)(W_dec + (e0 + j) * QDIM);
        float4 b = *(const float4*)(W_dec + (e0 + j) * QDIM + 4);
        wdec[j][0] = a.x; wdec[j][1] = a.y; wdec[j][2] = a.z; wdec[j][3] = a.w;
        wdec[j][4] = b.x; wdec[j][5] = b.y; wdec[j][6] = b.z; wdec[j][7] = b.w;
    }

    const int tok0 = blockIdx.x * T;

    // ---- load x for all T tokens (independent loads, deep in flight) ----
    float4 xv[T];
#pragma unroll
    for (int i = 0; i < T; ++i)
        xv[i] = *(const float4*)(x + (size_t)(tok0 + i) * EDIM + e0);

    // ---- encode partials: T*8 independent dot4 ----
    float partial[T][QDIM];
#pragma unroll
    for (int i = 0; i < T; ++i)
#pragma unroll
        for (int q = 0; q < QDIM; ++q)
            partial[i][q] = xv[i].x * wenc[q][0] + xv[i].y * wenc[q][1]
                          + xv[i].z * wenc[q][2] + xv[i].w * wenc[q][3];

    // ---- 64-lane butterfly all-reduce, 32-wide ILP per stage ----
#pragma unroll
    for (int off = 32; off >= 1; off >>= 1) {
#pragma unroll
        for (int i = 0; i < T; ++i)
#pragma unroll
            for (int q = 0; q < QDIM; ++q)
                partial[i][q] += __shfl_xor(partial[i][q], off, 64);
    }

    // ---- cross-wave combine: one barrier for all T tokens ----
    if (lane == 0) {
#pragma unroll
        for (int i = 0; i < T; ++i) {
            *(float4*)&red[i][wave][0] =
                make_float4(partial[i][0], partial[i][1], partial[i][2], partial[i][3]);
            *(float4*)&red[i][wave][4] =
                make_float4(partial[i][4], partial[i][5], partial[i][6], partial[i][7]);
        }
    }
    __syncthreads();

#pragma unroll
    for (int i = 0; i < T; ++i) {
        // sum the 4 wave partials (broadcast float4 reads, conflict-free)
        float4 lo = make_float4(0.f, 0.f, 0.f, 0.f);
        float4 hi = make_float4(0.f, 0.f, 0.f, 0.f);
#pragma unroll
        for (int w = 0; w < 4; ++w) {
            float4 a = *(const float4*)&red[i][w][0];
            float4 b = *(const float4*)&red[i][w][4];
            lo.x += a.x; lo.y += a.y; lo.z += a.z; lo.w += a.w;
            hi.x += b.x; hi.y += b.y; hi.z += b.z; hi.w += b.w;
        }
        float c[QDIM];
        c[0] = __cosf(lo.x); c[1] = __cosf(lo.y);
        c[2] = __cosf(lo.z); c[3] = __cosf(lo.w);
        c[4] = __cosf(hi.x); c[5] = __cosf(hi.y);
        c[6] = __cosf(hi.z); c[7] = __cosf(hi.w);

        // q-values: q[0] = c1*...*c7 ; q[i] = c0*...*ci
        float qv[QDIM];
        float q0 = c[1];
#pragma unroll
        for (int q = 2; q < QDIM; ++q) q0 *= c[q];
        qv[0] = q0;
        float p = c[0];
#pragma unroll
        for (int q = 1; q < QDIM; ++q) { p *= c[q]; qv[q] = p; }

        // decode + residual, coalesced float4 store
        float4 o = xv[i];
#pragma unroll
        for (int q = 0; q < QDIM; ++q) {
            o.x += qv[q] * wdec[0][q];
            o.y += qv[q] * wdec[1][q];
            o.z += qv[q] * wdec[2][q];
            o.w += qv[q] * wdec[3][q];
        }
        *(float4*)(out + (size_t)(tok0 + i) * EDIM + e0) = o;
    }
}

extern "C" void kernel_launch(void* const* d_in, const int* in_sizes, int n_in,
                              void* d_out, int out_size, void* d_ws, size_t ws_size,
                              hipStream_t stream) {
    const float* x     = (const float*)d_in[0];
    const float* W_enc = (const float*)d_in[1];
    const float* W_dec = (const float*)d_in[2];
    float* out         = (float*)d_out;

    hipLaunchKernelGGL(qattn_kernel, dim3(GRID), dim3(BLOCK), 0, stream,
                       x, W_enc, W_dec, out);
}

// Round 3
// 34.641 us; speedup vs baseline: 1.6386x; 1.4205x over previous
//
#include <hip/hip_runtime.h>

// QuantumAttention: out[b,s,e] = sum_q q[b,s,q] * W_dec[e,q] + x[b,s,e]
//   angles = x @ W_enc^T  ([B,S,Q]), c = cos(angles)
//   q[0] = prod(c[1..Q-1]);  q[i] = prod(c[0..i]) for i>=1
//
// R3: replace __shfl_xor butterfly (ds_bpermute -> LDS-pipe-bound, ~768
// wave-DS/block) with DPP v_add_f32 cascade on the VALU pipe
// (row_shr:1,2,4,8 + row_bcast:15,31 -> full sum in lane 63).
// Everything else identical to R2 (T=4, grid 4096, weights in regs).

#define EDIM 1024
#define QDIM 8
#define NTOK 16384
#define BLOCK 256
#define T 4                    // tokens per block
#define GRID (NTOK / T)        // 4096 blocks

// v += dpp_move(v); bound_ctrl=true -> out-of-range lanes contribute 0
template<int CTRL>
__device__ __forceinline__ float dpp_add(float v) {
    int m = __builtin_amdgcn_update_dpp(0, __float_as_int(v), CTRL, 0xF, 0xF, true);
    return v + __int_as_float(m);
}

// 64-lane sum, all on the VALU pipe; result valid in lane 63 only.
__device__ __forceinline__ float wave_sum63(float v) {
    v = dpp_add<0x111>(v);   // row_shr:1
    v = dpp_add<0x112>(v);   // row_shr:2
    v = dpp_add<0x114>(v);   // row_shr:4
    v = dpp_add<0x118>(v);   // row_shr:8  -> lane15 of each row16 = row sum
    v = dpp_add<0x142>(v);   // row_bcast:15 -> lane31 = rows0+1, lane63 = rows2+3
    v = dpp_add<0x143>(v);   // row_bcast:31 -> lane63 = all 64
    return v;
}

__global__ __launch_bounds__(BLOCK)
void qattn_kernel(const float* __restrict__ x,
                  const float* __restrict__ W_enc,   // [Q][E]
                  const float* __restrict__ W_dec,   // [E][Q]
                  float* __restrict__ out)
{
    __shared__ float red[T][4][QDIM];   // [tok][wave][q] = 128 floats

    const int t    = threadIdx.x;     // 0..255
    const int lane = t & 63;
    const int wave = t >> 6;
    const int e0   = t * 4;           // this thread's 4 embed elements

    // ---- weight slices into registers (once per block) ----
    float wenc[QDIM][4];
#pragma unroll
    for (int q = 0; q < QDIM; ++q) {
        float4 w = *(const float4*)(W_enc + q * EDIM + e0);
        wenc[q][0] = w.x; wenc[q][1] = w.y; wenc[q][2] = w.z; wenc[q][3] = w.w;
    }
    float wdec[4][QDIM];
#pragma unroll
    for (int j = 0; j < 4; ++j) {
        float4 a = *(const float4*)(W_dec + (e0 + j) * QDIM);
        float4 b = *(const float4*)(W_dec + (e0 + j) * QDIM + 4);
        wdec[j][0] = a.x; wdec[j][1] = a.y; wdec[j][2] = a.z; wdec[j][3] = a.w;
        wdec[j][4] = b.x; wdec[j][5] = b.y; wdec[j][6] = b.z; wdec[j][7] = b.w;
    }

    const int tok0 = blockIdx.x * T;

    // ---- load x for all T tokens (independent, deep in flight) ----
    float4 xv[T];
#pragma unroll
    for (int i = 0; i < T; ++i)
        xv[i] = *(const float4*)(x + (size_t)(tok0 + i) * EDIM + e0);

    // ---- encode partials: T*8 independent dot4 ----
    float partial[T][QDIM];
#pragma unroll
    for (int i = 0; i < T; ++i)
#pragma unroll
        for (int q = 0; q < QDIM; ++q)
            partial[i][q] = xv[i].x * wenc[q][0] + xv[i].y * wenc[q][1]
                          + xv[i].z * wenc[q][2] + xv[i].w * wenc[q][3];

    // ---- 64-lane reduce on the VALU pipe (DPP), sum lands in lane 63 ----
#pragma unroll
    for (int i = 0; i < T; ++i)
#pragma unroll
        for (int q = 0; q < QDIM; ++q)
            partial[i][q] = wave_sum63(partial[i][q]);

    // ---- cross-wave combine: lane 63 publishes, one barrier ----
    if (lane == 63) {
#pragma unroll
        for (int i = 0; i < T; ++i) {
            *(float4*)&red[i][wave][0] =
                make_float4(partial[i][0], partial[i][1], partial[i][2], partial[i][3]);
            *(float4*)&red[i][wave][4] =
                make_float4(partial[i][4], partial[i][5], partial[i][6], partial[i][7]);
        }
    }
    __syncthreads();

#pragma unroll
    for (int i = 0; i < T; ++i) {
        // sum the 4 wave partials (broadcast float4 reads, conflict-free)
        float4 lo = make_float4(0.f, 0.f, 0.f, 0.f);
        float4 hi = make_float4(0.f, 0.f, 0.f, 0.f);
#pragma unroll
        for (int w = 0; w < 4; ++w) {
            float4 a = *(const float4*)&red[i][w][0];
            float4 b = *(const float4*)&red[i][w][4];
            lo.x += a.x; lo.y += a.y; lo.z += a.z; lo.w += a.w;
            hi.x += b.x; hi.y += b.y; hi.z += b.z; hi.w += b.w;
        }
        float c[QDIM];
        c[0] = __cosf(lo.x); c[1] = __cosf(lo.y);
        c[2] = __cosf(lo.z); c[3] = __cosf(lo.w);
        c[4] = __cosf(hi.x); c[5] = __cosf(hi.y);
        c[6] = __cosf(hi.z); c[7] = __cosf(hi.w);

        // q-values: q[0] = c1*...*c7 ; q[i] = c0*...*ci
        float qv[QDIM];
        float q0 = c[1];
#pragma unroll
        for (int q = 2; q < QDIM; ++q) q0 *= c[q];
        qv[0] = q0;
        float p = c[0];
#pragma unroll
        for (int q = 1; q < QDIM; ++q) { p *= c[q]; qv[q] = p; }

        // decode + residual, coalesced float4 store
        float4 o = xv[i];
#pragma unroll
        for (int q = 0; q < QDIM; ++q) {
            o.x += qv[q] * wdec[0][q];
            o.y += qv[q] * wdec[1][q];
            o.z += qv[q] * wdec[2][q];
            o.w += qv[q] * wdec[3][q];
        }
        *(float4*)(out + (size_t)(tok0 + i) * EDIM + e0) = o;
    }
}

extern "C" void kernel_launch(void* const* d_in, const int* in_sizes, int n_in,
                              void* d_out, int out_size, void* d_ws, size_t ws_size,
                              hipStream_t stream) {
    const float* x     = (const float*)d_in[0];
    const float* W_enc = (const float*)d_in[1];
    const float* W_dec = (const float*)d_in[2];
    float* out         = (float*)d_out;

    hipLaunchKernelGGL(qattn_kernel, dim3(GRID), dim3(BLOCK), 0, stream,
                       x, W_enc, W_dec, out);
}